// Round 1
// 148.604 us; speedup vs baseline: 1.0478x; 1.0478x over previous
//
#include <hip/hip_runtime.h>

// Problem constants (match reference setup_inputs):
//   B=32, N=3072, F=256, P=3, S=N/P=1024
// out shape (B, S, F, 1) -> flat B*S*F floats.
constexpr int Bdim = 32;
constexpr int Ndim = 3072;
constexpr int Fdim = 256;
constexpr int Pdim = 3;
constexpr int Sdim = Ndim / Pdim;   // 1024
constexpr int WAVES_PER_BLOCK = 4;  // 256 threads

// ext_vector float4 so __builtin_nontemporal_load/store accept it directly.
typedef float f32x4 __attribute__((ext_vector_type(4)));

// Full 64-lane sum via DPP (VALU-only, no LDS pipe):
//   row_shr:1,2,4,8 -> inclusive prefix within each 16-lane row (lane15/31/47/63 = row sums)
//   row_bcast:15    -> lane31 += rowsum0 ; lane63 += rowsum2 (pre-op values)
//   row_bcast:31    -> lane63 = (rowsum2+rowsum3) + (rowsum0+rowsum1) = total
// then broadcast lane 63 to all lanes via readlane (SGPR).
__device__ __forceinline__ float wave_allsum(float v) {
    float t = v;
    int x;
    x = __builtin_amdgcn_update_dpp(0, __float_as_int(t), 0x111, 0xF, 0xF, true); // row_shr:1
    t += __int_as_float(x);
    x = __builtin_amdgcn_update_dpp(0, __float_as_int(t), 0x112, 0xF, 0xF, true); // row_shr:2
    t += __int_as_float(x);
    x = __builtin_amdgcn_update_dpp(0, __float_as_int(t), 0x114, 0xF, 0xF, true); // row_shr:4
    t += __int_as_float(x);
    x = __builtin_amdgcn_update_dpp(0, __float_as_int(t), 0x118, 0xF, 0xF, true); // row_shr:8
    t += __int_as_float(x);
    x = __builtin_amdgcn_update_dpp(0, __float_as_int(t), 0x142, 0xF, 0xF, true); // row_bcast:15
    t += __int_as_float(x);
    x = __builtin_amdgcn_update_dpp(0, __float_as_int(t), 0x143, 0xF, 0xF, true); // row_bcast:31
    t += __int_as_float(x);
    return __int_as_float(__builtin_amdgcn_readlane(__float_as_int(t), 63));
}

// One 64-lane wave per window (b, s). Lane i owns float4 at f = 4*i.
// x is streamed exactly once with zero reuse -> nontemporal (nt) loads bypass
// L2/L3 allocation; out is write-once -> nontemporal store. w (1 KB) stays a
// regular cached load so it remains L1/L2-resident across all 32768 waves.
__global__ __launch_bounds__(256) void gap_kernel(
    const float* __restrict__ x,   // [B, N, F]
    const float* __restrict__ w,   // [F]
    float* __restrict__ out)       // [B, S, F]
{
    const int lane = threadIdx.x & 63;
    const int wave = threadIdx.x >> 6;
    const int win  = blockIdx.x * WAVES_PER_BLOCK + wave;   // 0 .. B*S-1

    const size_t row0 = (size_t)win * (Pdim * Fdim) + lane * 4;  // B*N*F flat; windows are contiguous
    const f32x4 w4 = *(const f32x4*)(w + lane * 4);
    const f32x4 r0 = __builtin_nontemporal_load((const f32x4*)(x + row0));
    const f32x4 r1 = __builtin_nontemporal_load((const f32x4*)(x + row0 + Fdim));
    const f32x4 r2 = __builtin_nontemporal_load((const f32x4*)(x + row0 + 2 * Fdim));

    float p0 = r0.x * w4.x + r0.y * w4.y + r0.z * w4.z + r0.w * w4.w;
    float p1 = r1.x * w4.x + r1.y * w4.y + r1.z * w4.z + r1.w * w4.w;
    float p2 = r2.x * w4.x + r2.y * w4.y + r2.z * w4.z + r2.w * w4.w;

    // VALU-only cross-lane reduction (three independent chains, interleaved by scheduler).
    const float d0 = wave_allsum(p0);
    const float d1 = wave_allsum(p1);
    const float d2 = wave_allsum(p2);

    // Softmax over the 3 scores (bias is uniform -> cancels in softmax).
    const float m  = fmaxf(d0, fmaxf(d1, d2));
    float e0 = __expf(d0 - m);
    float e1 = __expf(d1 - m);
    float e2 = __expf(d2 - m);
    const float inv = 1.0f / (e0 + e1 + e2);
    e0 *= inv; e1 *= inv; e2 *= inv;

    f32x4 o;
    o.x = r0.x * e0 + r1.x * e1 + r2.x * e2;
    o.y = r0.y * e0 + r1.y * e1 + r2.y * e2;
    o.z = r0.z * e0 + r1.z * e1 + r2.z * e2;
    o.w = r0.w * e0 + r1.w * e1 + r2.w * e2;

    __builtin_nontemporal_store(o, (f32x4*)(out + (size_t)win * Fdim + lane * 4));
}

extern "C" void kernel_launch(void* const* d_in, const int* in_sizes, int n_in,
                              void* d_out, int out_size, void* d_ws, size_t ws_size,
                              hipStream_t stream) {
    const float* x = (const float*)d_in[0];   // [B, N, F] fp32
    const float* w = (const float*)d_in[1];   // [F] fp32
    // d_in[2] = W_bias — uniform additive constant, cancels in softmax.
    float* out = (float*)d_out;               // [B, S, F, 1] fp32

    const int n_windows = Bdim * Sdim;                    // 32768
    const int grid = n_windows / WAVES_PER_BLOCK;         // 8192
    gap_kernel<<<grid, WAVES_PER_BLOCK * 64, 0, stream>>>(x, w, out);
}

// Round 2
// 148.334 us; speedup vs baseline: 1.0497x; 1.0018x over previous
//
#include <hip/hip_runtime.h>

// Problem constants (match reference setup_inputs):
//   B=32, N=3072, F=256, P=3, S=N/P=1024
// out shape (B, S, F, 1) -> flat B*S*F floats.
constexpr int Bdim = 32;
constexpr int Ndim = 3072;
constexpr int Fdim = 256;
constexpr int Pdim = 3;
constexpr int Sdim = Ndim / Pdim;    // 1024
constexpr int WAVES_PER_BLOCK = 4;   // 256 threads
constexpr int WINDOWS_PER_WAVE = 2;  // wave reads 6 KB contiguous, writes 2 KB

// ext_vector float4 so __builtin_nontemporal_load/store accept it directly.
typedef float f32x4 __attribute__((ext_vector_type(4)));

// Full 64-lane sum via DPP (VALU-only, no LDS pipe):
//   row_shr:1,2,4,8 -> inclusive prefix within each 16-lane row (lane15/31/47/63 = row sums)
//   row_bcast:15    -> lane31 += rowsum0 ; lane63 += rowsum2 (pre-op values)
//   row_bcast:31    -> lane63 = (rowsum2+rowsum3) + (rowsum0+rowsum1) = total
// then broadcast lane 63 to all lanes via readlane (SGPR).
__device__ __forceinline__ float wave_allsum(float v) {
    float t = v;
    int x;
    x = __builtin_amdgcn_update_dpp(0, __float_as_int(t), 0x111, 0xF, 0xF, true); // row_shr:1
    t += __int_as_float(x);
    x = __builtin_amdgcn_update_dpp(0, __float_as_int(t), 0x112, 0xF, 0xF, true); // row_shr:2
    t += __int_as_float(x);
    x = __builtin_amdgcn_update_dpp(0, __float_as_int(t), 0x114, 0xF, 0xF, true); // row_shr:4
    t += __int_as_float(x);
    x = __builtin_amdgcn_update_dpp(0, __float_as_int(t), 0x118, 0xF, 0xF, true); // row_shr:8
    t += __int_as_float(x);
    x = __builtin_amdgcn_update_dpp(0, __float_as_int(t), 0x142, 0xF, 0xF, true); // row_bcast:15
    t += __int_as_float(x);
    x = __builtin_amdgcn_update_dpp(0, __float_as_int(t), 0x143, 0xF, 0xF, true); // row_bcast:31
    t += __int_as_float(x);
    return __int_as_float(__builtin_amdgcn_readlane(__float_as_int(t), 63));
}

__device__ __forceinline__ float dot4(f32x4 a, f32x4 b) {
    return a.x * b.x + a.y * b.y + a.z * b.z + a.w * b.w;
}

// One 64-lane wave per TWO consecutive windows. Lane i owns float4 at f = 4*i.
// The wave streams one contiguous 6 KB span of x (6 x dwordx4-per-lane loads
// issued back-to-back -> deep memory-level parallelism), nontemporal so the
// zero-reuse stream bypasses L2/L3 allocation. w (1 KB) stays cached.
__global__ __launch_bounds__(256) void gap_kernel(
    const float* __restrict__ x,   // [B, N, F]
    const float* __restrict__ w,   // [F]
    float* __restrict__ out)       // [B, S, F]
{
    const int lane = threadIdx.x & 63;
    const int wave = threadIdx.x >> 6;
    const int win0 = (blockIdx.x * WAVES_PER_BLOCK + wave) * WINDOWS_PER_WAVE;

    const size_t base = (size_t)win0 * (Pdim * Fdim) + lane * 4;
    const f32x4 w4 = *(const f32x4*)(w + lane * 4);

    // Issue all 6 loads up front (contiguous 6 KB wave-level span).
    const f32x4 a0 = __builtin_nontemporal_load((const f32x4*)(x + base));
    const f32x4 a1 = __builtin_nontemporal_load((const f32x4*)(x + base + Fdim));
    const f32x4 a2 = __builtin_nontemporal_load((const f32x4*)(x + base + 2 * Fdim));
    const f32x4 b0 = __builtin_nontemporal_load((const f32x4*)(x + base + 3 * Fdim));
    const f32x4 b1 = __builtin_nontemporal_load((const f32x4*)(x + base + 4 * Fdim));
    const f32x4 b2 = __builtin_nontemporal_load((const f32x4*)(x + base + 5 * Fdim));

    // Six independent DPP reduction chains interleave on the VALU.
    const float da0 = wave_allsum(dot4(a0, w4));
    const float da1 = wave_allsum(dot4(a1, w4));
    const float da2 = wave_allsum(dot4(a2, w4));
    const float db0 = wave_allsum(dot4(b0, w4));
    const float db1 = wave_allsum(dot4(b1, w4));
    const float db2 = wave_allsum(dot4(b2, w4));

    // Softmax over each window's 3 scores (uniform bias cancels).
    const float ma = fmaxf(da0, fmaxf(da1, da2));
    float ea0 = __expf(da0 - ma), ea1 = __expf(da1 - ma), ea2 = __expf(da2 - ma);
    const float inva = 1.0f / (ea0 + ea1 + ea2);
    ea0 *= inva; ea1 *= inva; ea2 *= inva;

    const float mb = fmaxf(db0, fmaxf(db1, db2));
    float eb0 = __expf(db0 - mb), eb1 = __expf(db1 - mb), eb2 = __expf(db2 - mb);
    const float invb = 1.0f / (eb0 + eb1 + eb2);
    eb0 *= invb; eb1 *= invb; eb2 *= invb;

    f32x4 oa, ob;
    oa.x = a0.x * ea0 + a1.x * ea1 + a2.x * ea2;
    oa.y = a0.y * ea0 + a1.y * ea1 + a2.y * ea2;
    oa.z = a0.z * ea0 + a1.z * ea1 + a2.z * ea2;
    oa.w = a0.w * ea0 + a1.w * ea1 + a2.w * ea2;
    ob.x = b0.x * eb0 + b1.x * eb1 + b2.x * eb2;
    ob.y = b0.y * eb0 + b1.y * eb1 + b2.y * eb2;
    ob.z = b0.z * eb0 + b1.z * eb1 + b2.z * eb2;
    ob.w = b0.w * eb0 + b1.w * eb1 + b2.w * eb2;

    float* o = out + (size_t)win0 * Fdim + lane * 4;
    __builtin_nontemporal_store(oa, (f32x4*)o);
    __builtin_nontemporal_store(ob, (f32x4*)(o + Fdim));
}

extern "C" void kernel_launch(void* const* d_in, const int* in_sizes, int n_in,
                              void* d_out, int out_size, void* d_ws, size_t ws_size,
                              hipStream_t stream) {
    const float* x = (const float*)d_in[0];   // [B, N, F] fp32
    const float* w = (const float*)d_in[1];   // [F] fp32
    // d_in[2] = W_bias — uniform additive constant, cancels in softmax.
    float* out = (float*)d_out;               // [B, S, F, 1] fp32

    const int n_windows = Bdim * Sdim;                               // 32768
    const int grid = n_windows / (WAVES_PER_BLOCK * WINDOWS_PER_WAVE); // 4096
    gap_kernel<<<grid, WAVES_PER_BLOCK * 64, 0, stream>>>(x, w, out);
}